// Round 1
// 414.571 us; speedup vs baseline: 1.0315x; 1.0315x over previous
//
#include <hip/hip_runtime.h>

// Per-row L2 norm: 16384 rows x 4096 cols, fp32 in/out.
// One 256-thread block per row; each thread holds 16 floats (4x float4) in
// registers so each element is read from HBM exactly once.
// This revision: nontemporal (streaming) loads/stores — zero reuse, so tell
// TCC not to retain lines. Targets the last ~12% gap to the BW ceiling.

constexpr int COLS = 4096;
constexpr int TPB  = 256;          // 4 waves of 64
constexpr int F4_PER_ROW = COLS / 4;   // 1024 float4
constexpr int F4_PER_THR = F4_PER_ROW / TPB; // 4

// clang ext vector so __builtin_nontemporal_{load,store} accepts it
typedef float v4f __attribute__((ext_vector_type(4)));

__global__ __launch_bounds__(TPB) void l2norm_rows(const float* __restrict__ in,
                                                   float* __restrict__ out) {
    const int row = blockIdx.x;
    const v4f* __restrict__ inrow =
        reinterpret_cast<const v4f*>(in + (size_t)row * COLS);
    v4f* __restrict__ outrow =
        reinterpret_cast<v4f*>(out + (size_t)row * COLS);

    // Coalesced: lane i reads float4 at [tid + k*256], nontemporal
    v4f v[F4_PER_THR];
    float s = 0.0f;
#pragma unroll
    for (int k = 0; k < F4_PER_THR; ++k) {
        v[k] = __builtin_nontemporal_load(&inrow[threadIdx.x + k * TPB]);
        s += v[k].x * v[k].x + v[k].y * v[k].y + v[k].z * v[k].z + v[k].w * v[k].w;
    }

    // Wave-level reduction (64 lanes)
#pragma unroll
    for (int off = 32; off > 0; off >>= 1)
        s += __shfl_down(s, off, 64);

    // Cross-wave combine (4 waves)
    __shared__ float ws[TPB / 64];
    const int lane = threadIdx.x & 63;
    const int wave = threadIdx.x >> 6;
    if (lane == 0) ws[wave] = s;
    __syncthreads();
    const float total = ws[0] + ws[1] + ws[2] + ws[3];

    const float r = rsqrtf(total);   // v_rsq_f32, ~1 ulp; threshold is 1.7e-3

#pragma unroll
    for (int k = 0; k < F4_PER_THR; ++k) {
        v4f o = v[k] * r;
        __builtin_nontemporal_store(o, &outrow[threadIdx.x + k * TPB]);
    }
}

extern "C" void kernel_launch(void* const* d_in, const int* in_sizes, int n_in,
                              void* d_out, int out_size, void* d_ws, size_t ws_size,
                              hipStream_t stream) {
    const float* in = (const float*)d_in[0];
    float* out = (float*)d_out;
    const int rows = in_sizes[0] / COLS;   // 16384
    l2norm_rows<<<rows, TPB, 0, stream>>>(in, out);
}